// Round 13
// baseline (338.487 us; speedup 1.0000x reference)
//
#include <hip/hip_runtime.h>
#include <math.h>

#define N_NODES 100000
#define N_EDGES 1280000
#define DIM 64
#define N_GRAPHS 1000
#define BN_EPS 1e-5f
#define NB 392            // buckets = dst>>8; 392*256 = 100352 >= N_NODES
#define P1B 256           // pass-1 histogram blocks; 256*5000 = 1.28M exactly
#define P1E 5000
#define SB 400            // stats blocks (400*250 = 100k rows, contiguous spans)
#define WIN 128           // edges per gather wave window; N_EDGES/WIN = 10000
#define NWIN (N_EDGES / WIN)
#define GU 16             // edge unroll inside a window (16 row-gathers in flight)
#define NSLOT 32          // BN-stat partial slots

// ---- bf16 helpers (top 16 bits of fp32, RTN) ----
__device__ __forceinline__ unsigned int bf16_rtn2(float a, float b) {
    unsigned int ua = __float_as_uint(a);
    unsigned int ub = __float_as_uint(b);
    ua = (ua + 0x7FFFu + ((ua >> 16) & 1u)) >> 16;
    ub = (ub + 0x7FFFu + ((ub >> 16) & 1u)) >> 16;
    return ua | (ub << 16);
}
__device__ __forceinline__ unsigned short bf16r(float a) {
    unsigned int u = __float_as_uint(a);
    return (unsigned short)((u + 0x7FFFu + ((u >> 16) & 1u)) >> 16);
}
__device__ __forceinline__ float bfup(unsigned short u) {
    return __uint_as_float(((unsigned int)u) << 16);
}

// ---------------- pass 1a: bucket histogram + BN-input stats + graph boundaries ---------
__global__ __launch_bounds__(256) void k_p1hist(const int* __restrict__ ei,
                                                const int* __restrict__ batch,
                                                const float* __restrict__ X,
                                                int* __restrict__ bh,
                                                int* __restrict__ start,
                                                float* __restrict__ gsum,
                                                float* __restrict__ gsumsq) {
    int t = threadIdx.x;
    if (blockIdx.x < P1B) {
        __shared__ int hist[NB];
        for (int b = t; b < NB; b += 256) hist[b] = 0;
        __syncthreads();
        int e0 = blockIdx.x * P1E;
        #pragma unroll 4
        for (int e = e0 + t; e < e0 + P1E; e += 256)
            atomicAdd(&hist[ei[N_EDGES + e] >> 8], 1);
        __syncthreads();
        for (int b = t; b < NB; b += 256) bh[b * P1B + blockIdx.x] = hist[b];
    } else if (blockIdx.x < P1B + SB) {
        int grp = blockIdx.x - P1B;
        int j = t & 63, rg = t >> 6;
        int base = grp * 250;
        float s = 0.f, s2 = 0.f;
        for (int i = base + rg; i < base + 250; i += 4) {
            float v = X[i * DIM + j];
            s += v; s2 += v * v;
        }
        __shared__ float ls[256], ls2[256];
        ls[t] = s; ls2[t] = s2;
        __syncthreads();
        if (t < 64) {
            int slot = (grp & (NSLOT - 1)) * DIM;
            s  = ls[j]  + ls[64 + j]  + ls[128 + j]  + ls[192 + j];
            s2 = ls2[j] + ls2[64 + j] + ls2[128 + j] + ls2[192 + j];
            atomicAdd(&gsum[slot + j], s);
            atomicAdd(&gsumsq[slot + j], s2);
        }
    } else {
        int i = (blockIdx.x - P1B - SB) * 256 + t;
        if (i < N_NODES) {
            int cur = batch[i];
            if (i == 0) { for (int q = 0; q <= cur; q++) start[q] = 0; }
            else {
                int prev = batch[i - 1];
                for (int q = prev + 1; q <= cur; q++) start[q] = i;
            }
            if (i == N_NODES - 1)
                for (int q = cur + 1; q <= N_GRAPHS; q++) start[q] = N_NODES;
        }
    }
}

// ---------------- scan of bh[100352] ----------------
__global__ void k_scan1(const int* __restrict__ bh, int* __restrict__ iscan,
                        int* __restrict__ bsum) {
    __shared__ int ls[256];
    int i = blockIdx.x * 256 + threadIdx.x;
    int v = bh[i];
    ls[threadIdx.x] = v;
    __syncthreads();
    for (int off = 1; off < 256; off <<= 1) {
        int tv = (threadIdx.x >= off) ? ls[threadIdx.x - off] : 0;
        __syncthreads();
        ls[threadIdx.x] += tv;
        __syncthreads();
    }
    iscan[i] = ls[threadIdx.x];
    if (threadIdx.x == 255) bsum[blockIdx.x] = ls[255];
}

__global__ void k_scan2(const int* __restrict__ bsum, int* __restrict__ boff) {
    __shared__ int ls[512];
    int t = threadIdx.x;
    int v0 = (t < NB) ? bsum[t] : 0;
    ls[t] = v0;
    __syncthreads();
    for (int off = 1; off < 512; off <<= 1) {
        int v = (t >= off) ? ls[t - off] : 0;
        __syncthreads();
        ls[t] += v;
        __syncthreads();
    }
    if (t < NB) boff[t] = ls[t] - v0;
}

// ---------------- pass 1b: scatter edges into bucket-major tmp (LDS cursors) ------------
__global__ __launch_bounds__(256) void k_p1scat(const int* __restrict__ ei,
                                                const int* __restrict__ bh,
                                                const int* __restrict__ iscan,
                                                const int* __restrict__ boff,
                                                int2* __restrict__ tmp) {
    __shared__ int cur[NB];
    int blk = blockIdx.x;
    for (int b = threadIdx.x; b < NB; b += 256) {
        int i = b * P1B + blk;
        cur[b] = boff[b] + iscan[i] - bh[i];
    }
    __syncthreads();
    int e0 = blk * P1E;
    for (int e = e0 + threadIdx.x; e < e0 + P1E; e += 256) {
        int r = ei[e], c = ei[N_EDGES + e];
        int pos = atomicAdd(&cur[c >> 8], 1);
        tmp[pos] = make_int2(r, c);
    }
}

// ---------------- pass 2a: per-bucket histogram -> dinv, rowstart, winnode --------------
__global__ __launch_bounds__(256) void k_p2a(const int2* __restrict__ tmp,
                                             const int* __restrict__ bh,
                                             const int* __restrict__ iscan,
                                             const int* __restrict__ boff,
                                             int* __restrict__ rowstart,
                                             float* __restrict__ dinv,
                                             int* __restrict__ winnode) {
    int b = blockIdx.x, t = threadIdx.x;
    int bstart = boff[b] + iscan[b * 256] - bh[b * 256];
    int bend = (b == NB - 1) ? N_EDGES
                             : (boff[b + 1] + iscan[(b + 1) * 256] - bh[(b + 1) * 256]);
    __shared__ int cnt[256], scn[256];
    cnt[t] = 0;
    __syncthreads();
    for (int e = bstart + t; e < bend; e += 256)
        atomicAdd(&cnt[tmp[e].y & 255], 1);
    __syncthreads();
    scn[t] = cnt[t];
    __syncthreads();
    for (int off = 1; off < 256; off <<= 1) {
        int v = (t >= off) ? scn[t - off] : 0;
        __syncthreads();
        scn[t] += v;
        __syncthreads();
    }
    int node = b * 256 + t;
    int rs = bstart + scn[t] - cnt[t];
    if (node <= N_NODES) rowstart[node] = rs;
    if (node < N_NODES) {
        int deg = cnt[t];
        dinv[node] = 1.0f / sqrtf((float)(deg + 1));
        int re = rs + deg;
        for (int w = (rs + WIN - 1) / WIN; w * WIN < re; ++w) winnode[w] = node;
    }
}

// ---------------- pass 2b: within-bucket sort -> final CSR (src only, no weights) -------
__global__ __launch_bounds__(256) void k_p2b(const int2* __restrict__ tmp,
                                             const int* __restrict__ bh,
                                             const int* __restrict__ iscan,
                                             const int* __restrict__ boff,
                                             const int* __restrict__ rowstart,
                                             int* __restrict__ csr) {
    int b = blockIdx.x, t = threadIdx.x;
    int bstart = boff[b] + iscan[b * 256] - bh[b * 256];
    int bend = (b == NB - 1) ? N_EDGES
                             : (boff[b + 1] + iscan[(b + 1) * 256] - bh[(b + 1) * 256]);
    __shared__ int curs[256];
    int node = b * 256 + t;
    curs[t] = (node < N_NODES) ? rowstart[node] : 0;
    __syncthreads();
    for (int e = bstart + t; e < bend; e += 256) {
        int2 rec = tmp[e];
        int pos = atomicAdd(&curs[rec.y & 255], 1);
        csr[pos] = rec.x;
    }
}

// ---------------- BN fold: reduce 32 slots, scale/cshift, re-zero slots ----------------
__global__ void k_bnfold(float* __restrict__ gsum, float* __restrict__ gsumsq,
                         const float* __restrict__ g, const float* __restrict__ b,
                         const float* __restrict__ W,
                         float* __restrict__ scale, float* __restrict__ cshift) {
    int j = threadIdx.x;
    float ms = 0.f, m2 = 0.f;
    for (int k = 0; k < NSLOT; k++) {
        ms += gsum[k * DIM + j];   gsum[k * DIM + j] = 0.f;
        m2 += gsumsq[k * DIM + j]; gsumsq[k * DIM + j] = 0.f;
    }
    float mean = ms * (1.0f / N_NODES);
    float var  = m2 * (1.0f / N_NODES) - mean * mean;
    float inv  = 1.0f / sqrtf(var + BN_EPS);
    float sc   = g[j] * inv;
    scale[j] = sc;
    __shared__ float shl[64];
    shl[j] = b[j] - mean * sc;
    __syncthreads();
    float s = 0.f;
    for (int k = 0; k < DIM; k++) s += shl[k] * W[k * DIM + j];
    cshift[j] = s;
}

__global__ void k_bnfinal(const float* __restrict__ gsum, const float* __restrict__ gsumsq,
                          const float* __restrict__ g, const float* __restrict__ b,
                          float* __restrict__ scale, float* __restrict__ shift) {
    int j = threadIdx.x;
    float ms = 0.f, m2 = 0.f;
    for (int k = 0; k < NSLOT; k++) { ms += gsum[k * DIM + j]; m2 += gsumsq[k * DIM + j]; }
    float mean = ms * (1.0f / N_NODES);
    float var  = m2 * (1.0f / N_NODES) - mean * mean;
    float inv  = 1.0f / sqrtf(var + BN_EPS);
    float sc   = g[j] * inv;
    scale[j] = sc;
    shift[j] = b[j] - mean * sc;
}

// ---------------- GEMM (fp32 A): T' = ((X*scale)@W + cshift)*dinv[row], bf16 ------------
__global__ __launch_bounds__(256) void k_gemm_f32(const float* __restrict__ X,
                                                  const float* __restrict__ W,
                                                  const float* __restrict__ scale,
                                                  const float* __restrict__ cshift,
                                                  const float* __restrict__ dinv,
                                                  unsigned short* __restrict__ T) {
    __shared__ float Wl[64 * 64];
    __shared__ float Al[64 * 65];
    for (int t = threadIdx.x; t < 4096; t += 256) Wl[t] = W[t] * scale[t >> 6];
    int row0 = blockIdx.x * 64;
    for (int t = threadIdx.x; t < 4096; t += 256) {
        int r = t >> 6, k = t & 63;
        int i = row0 + r;
        Al[r * 65 + k] = (i < N_NODES) ? X[(size_t)i * DIM + k] : 0.f;
    }
    __syncthreads();
    int r = threadIdx.x & 63;
    int q = threadIdx.x >> 6;
    float acc[16];
    #pragma unroll
    for (int jj = 0; jj < 16; jj++) acc[jj] = cshift[q * 16 + jj];
    #pragma unroll 4
    for (int k = 0; k < 64; k++) {
        float a = Al[r * 65 + k];
        const float4* wv = (const float4*)&Wl[k * 64 + q * 16];
        float4 w0 = wv[0], w1 = wv[1], w2 = wv[2], w3 = wv[3];
        acc[0]  += a * w0.x; acc[1]  += a * w0.y; acc[2]  += a * w0.z; acc[3]  += a * w0.w;
        acc[4]  += a * w1.x; acc[5]  += a * w1.y; acc[6]  += a * w1.z; acc[7]  += a * w1.w;
        acc[8]  += a * w2.x; acc[9]  += a * w2.y; acc[10] += a * w2.z; acc[11] += a * w2.w;
        acc[12] += a * w3.x; acc[13] += a * w3.y; acc[14] += a * w3.z; acc[15] += a * w3.w;
    }
    int i = row0 + r;
    if (i < N_NODES) {
        float dv = dinv[i];
        unsigned int pk[8];
        #pragma unroll
        for (int jj = 0; jj < 8; jj++)
            pk[jj] = bf16_rtn2(acc[2 * jj] * dv, acc[2 * jj + 1] * dv);
        uint4* outv = (uint4*)&T[(size_t)i * DIM + q * 16];
        outv[0] = make_uint4(pk[0], pk[1], pk[2], pk[3]);
        outv[1] = make_uint4(pk[4], pk[5], pk[6], pk[7]);
    }
}

// ---------------- GEMM (bf16 A): T' = ((H*scale)@W + cshift)*dinv[row], bf16 ------------
__global__ __launch_bounds__(256) void k_gemm_b16(const unsigned short* __restrict__ X,
                                                  const float* __restrict__ W,
                                                  const float* __restrict__ scale,
                                                  const float* __restrict__ cshift,
                                                  const float* __restrict__ dinv,
                                                  unsigned short* __restrict__ T) {
    __shared__ float Wl[64 * 64];
    __shared__ float Al[64 * 65];
    for (int t = threadIdx.x; t < 4096; t += 256) Wl[t] = W[t] * scale[t >> 6];
    int row0 = blockIdx.x * 64;
    for (int t = threadIdx.x; t < 4096; t += 256) {
        int r = t >> 6, k = t & 63;
        int i = row0 + r;
        Al[r * 65 + k] = (i < N_NODES) ? bfup(X[(size_t)i * DIM + k]) : 0.f;
    }
    __syncthreads();
    int r = threadIdx.x & 63;
    int q = threadIdx.x >> 6;
    float acc[16];
    #pragma unroll
    for (int jj = 0; jj < 16; jj++) acc[jj] = cshift[q * 16 + jj];
    #pragma unroll 4
    for (int k = 0; k < 64; k++) {
        float a = Al[r * 65 + k];
        const float4* wv = (const float4*)&Wl[k * 64 + q * 16];
        float4 w0 = wv[0], w1 = wv[1], w2 = wv[2], w3 = wv[3];
        acc[0]  += a * w0.x; acc[1]  += a * w0.y; acc[2]  += a * w0.z; acc[3]  += a * w0.w;
        acc[4]  += a * w1.x; acc[5]  += a * w1.y; acc[6]  += a * w1.z; acc[7]  += a * w1.w;
        acc[8]  += a * w2.x; acc[9]  += a * w2.y; acc[10] += a * w2.z; acc[11] += a * w2.w;
        acc[12] += a * w3.x; acc[13] += a * w3.y; acc[14] += a * w3.z; acc[15] += a * w3.w;
    }
    int i = row0 + r;
    if (i < N_NODES) {
        float dv = dinv[i];
        unsigned int pk[8];
        #pragma unroll
        for (int jj = 0; jj < 8; jj++)
            pk[jj] = bf16_rtn2(acc[2 * jj] * dv, acc[2 * jj + 1] * dv);
        uint4* outv = (uint4*)&T[(size_t)i * DIM + q * 16];
        outv[0] = make_uint4(pk[0], pk[1], pk[2], pk[3]);
        outv[1] = make_uint4(pk[4], pk[5], pk[6], pk[7]);
    }
}

// ---------------- zero C rows of straddler nodes (idempotent) ----------------
__global__ __launch_bounds__(256) void k_zstrad(const int* __restrict__ rowstart,
                                                const int* __restrict__ winnode,
                                                float* __restrict__ C) {
    int lane = threadIdx.x & 63;
    int w = blockIdx.x * 4 + (threadIdx.x >> 6);
    int n = winnode[w];
    if (rowstart[n] < w * WIN)
        C[(size_t)n * DIM + lane] = 0.f;
}

// ---------------- gather layer 1: h = relu((Σ T'[src] + T'[i])·dinv[i] + bias) ----------
__global__ __launch_bounds__(256) void k_gather1(const unsigned short* __restrict__ T,
                                                 const float* __restrict__ dinv,
                                                 const int* __restrict__ rowstart,
                                                 const int* __restrict__ winnode,
                                                 const int* __restrict__ csr,
                                                 const float* __restrict__ bias,
                                                 float* __restrict__ C,
                                                 unsigned short* __restrict__ H,
                                                 float* __restrict__ gsum,
                                                 float* __restrict__ gsumsq) {
    int lane = threadIdx.x & 63;
    int w = blockIdx.x * 4 + (threadIdx.x >> 6);
    float bb = bias[lane];
    float s = 0.f, s2 = 0.f;
    int e = w * WIN;
    const int eend = e + WIN;
    int i  = __builtin_amdgcn_readfirstlane(winnode[w]);
    int re = __builtin_amdgcn_readfirstlane(rowstart[i + 1]);
    bool part = __builtin_amdgcn_readfirstlane(rowstart[i]) < e;
    float acc = 0.f;
    for (; e < eend; e += GU) {
        int src[GU];
        int eu = __builtin_amdgcn_readfirstlane(e);
        #pragma unroll
        for (int u = 0; u < GU; u++) src[u] = csr[eu + u];
        float tv[GU];
        #pragma unroll
        for (int u = 0; u < GU; u++) tv[u] = bfup(T[(size_t)src[u] * DIM + lane]);
        #pragma unroll
        for (int u = 0; u < GU; u++) {
            while (e + u == re) {
                if (part) { atomicAdd(&C[(size_t)i * DIM + lane], acc); part = false; }
                else {
                    float di = dinv[i];
                    float h = fmaxf((acc + bfup(T[(size_t)i * DIM + lane])) * di + bb, 0.f);
                    H[(size_t)i * DIM + lane] = bf16r(h);
                    s += h; s2 += h * h;
                }
                acc = 0.f; ++i;
                re = __builtin_amdgcn_readfirstlane(rowstart[i + 1]);
            }
            acc += tv[u];
        }
    }
    if (part || re > eend) atomicAdd(&C[(size_t)i * DIM + lane], acc);
    else {
        float di = dinv[i];
        float h = fmaxf((acc + bfup(T[(size_t)i * DIM + lane])) * di + bb, 0.f);
        H[(size_t)i * DIM + lane] = bf16r(h);
        s += h; s2 += h * h;
    }
    __shared__ float ls[256], ls2[256];
    ls[threadIdx.x] = s; ls2[threadIdx.x] = s2;
    __syncthreads();
    if (threadIdx.x < 64) {
        int j = threadIdx.x;
        int slot = (blockIdx.x & (NSLOT - 1)) * DIM;
        atomicAdd(&gsum[slot + j],   ls[j] + ls[64 + j] + ls[128 + j] + ls[192 + j]);
        atomicAdd(&gsumsq[slot + j], ls2[j] + ls2[64 + j] + ls2[128 + j] + ls2[192 + j]);
    }
}

// ---------------- gather layer 2: h -> pool(run-flush) + stats ----------------
__global__ __launch_bounds__(256) void k_gather2(const unsigned short* __restrict__ T,
                                                 const float* __restrict__ dinv,
                                                 const int* __restrict__ rowstart,
                                                 const int* __restrict__ winnode,
                                                 const int* __restrict__ csr,
                                                 const float* __restrict__ bias,
                                                 const int* __restrict__ batch,
                                                 float* __restrict__ C,
                                                 float* __restrict__ pool,
                                                 float* __restrict__ gsum,
                                                 float* __restrict__ gsumsq) {
    int lane = threadIdx.x & 63;
    int w = blockIdx.x * 4 + (threadIdx.x >> 6);
    float bb = bias[lane];
    float s = 0.f, s2 = 0.f, ps = 0.f;
    int cur_g = -1;
    int e = w * WIN;
    const int eend = e + WIN;
    int i  = __builtin_amdgcn_readfirstlane(winnode[w]);
    int re = __builtin_amdgcn_readfirstlane(rowstart[i + 1]);
    bool part = __builtin_amdgcn_readfirstlane(rowstart[i]) < e;
    float acc = 0.f;
    for (; e < eend; e += GU) {
        int src[GU];
        int eu = __builtin_amdgcn_readfirstlane(e);
        #pragma unroll
        for (int u = 0; u < GU; u++) src[u] = csr[eu + u];
        float tv[GU];
        #pragma unroll
        for (int u = 0; u < GU; u++) tv[u] = bfup(T[(size_t)src[u] * DIM + lane]);
        #pragma unroll
        for (int u = 0; u < GU; u++) {
            while (e + u == re) {
                if (part) { atomicAdd(&C[(size_t)i * DIM + lane], acc); part = false; }
                else {
                    float di = dinv[i];
                    float h = fmaxf((acc + bfup(T[(size_t)i * DIM + lane])) * di + bb, 0.f);
                    s += h; s2 += h * h;
                    int g = batch[i];
                    if (g != cur_g) {
                        if (cur_g >= 0) atomicAdd(&pool[(size_t)cur_g * DIM + lane], ps);
                        ps = 0.f; cur_g = g;
                    }
                    ps += h;
                }
                acc = 0.f; ++i;
                re = __builtin_amdgcn_readfirstlane(rowstart[i + 1]);
            }
            acc += tv[u];
        }
    }
    if (part || re > eend) atomicAdd(&C[(size_t)i * DIM + lane], acc);
    else {
        float di = dinv[i];
        float h = fmaxf((acc + bfup(T[(size_t)i * DIM + lane])) * di + bb, 0.f);
        s += h; s2 += h * h;
        int g = batch[i];
        if (g != cur_g) {
            if (cur_g >= 0) atomicAdd(&pool[(size_t)cur_g * DIM + lane], ps);
            ps = 0.f; cur_g = g;
        }
        ps += h;
    }
    if (cur_g >= 0) atomicAdd(&pool[(size_t)cur_g * DIM + lane], ps);
    __shared__ float ls[256], ls2[256];
    ls[threadIdx.x] = s; ls2[threadIdx.x] = s2;
    __syncthreads();
    if (threadIdx.x < 64) {
        int j = threadIdx.x;
        int slot = (blockIdx.x & (NSLOT - 1)) * DIM;
        atomicAdd(&gsum[slot + j],   ls[j] + ls[64 + j] + ls[128 + j] + ls[192 + j]);
        atomicAdd(&gsumsq[slot + j], ls2[j] + ls2[64 + j] + ls2[128 + j] + ls2[192 + j]);
    }
}

// ---------------- straddler + boundary-deg0 finish, layer 1 (-> H + stats) --------------
__global__ __launch_bounds__(256) void k_strad1(const float* __restrict__ C,
                                                const unsigned short* __restrict__ T,
                                                const float* __restrict__ dinv,
                                                const int* __restrict__ rowstart,
                                                const int* __restrict__ winnode,
                                                const float* __restrict__ bias,
                                                unsigned short* __restrict__ H,
                                                float* __restrict__ gsum,
                                                float* __restrict__ gsumsq) {
    int lane = threadIdx.x & 63;
    int wv = threadIdx.x >> 6;
    float bb = bias[lane];
    float s = 0.f, s2 = 0.f;
    __shared__ int anyw;
    if (threadIdx.x == 0) anyw = 0;
    __syncthreads();
    if (blockIdx.x < NWIN / 4) {
        int w = blockIdx.x * 4 + wv;
        int n = winnode[w];
        int rs = rowstart[n];
        if (w == rs / WIN + 1) {
            float di = dinv[n];
            float h = fmaxf((C[(size_t)n * DIM + lane]
                             + bfup(T[(size_t)n * DIM + lane])) * di + bb, 0.f);
            H[(size_t)n * DIM + lane] = bf16r(h);
            s += h; s2 += h * h;
            anyw = 1;
        }
    } else {
        int base = (blockIdx.x - NWIN / 4) * 256 + wv * 64;
        int nb = base + lane;
        int d0 = 0;
        if (nb < N_NODES)
            d0 = (rowstart[nb + 1] == rowstart[nb]) && ((rowstart[nb] & (WIN - 1)) == 0);
        unsigned long long m = __ballot(d0);
        while (m) {
            int b = __builtin_ctzll(m);
            m &= m - 1;
            int n = base + b;
            float di = dinv[n];
            float h = fmaxf(bfup(T[(size_t)n * DIM + lane]) * di + bb, 0.f);
            H[(size_t)n * DIM + lane] = bf16r(h);
            s += h; s2 += h * h;
            anyw = 1;
        }
    }
    __shared__ float ls[256], ls2[256];
    ls[threadIdx.x] = s; ls2[threadIdx.x] = s2;
    __syncthreads();
    if (anyw && threadIdx.x < 64) {
        int j = threadIdx.x;
        int slot = (blockIdx.x & (NSLOT - 1)) * DIM;
        atomicAdd(&gsum[slot + j],   ls[j] + ls[64 + j] + ls[128 + j] + ls[192 + j]);
        atomicAdd(&gsumsq[slot + j], ls2[j] + ls2[64 + j] + ls2[128 + j] + ls2[192 + j]);
    }
}

// ---------------- straddler + boundary-deg0 finish, layer 2 (-> pool + stats) -----------
__global__ __launch_bounds__(256) void k_strad2(const float* __restrict__ C,
                                                const unsigned short* __restrict__ T,
                                                const float* __restrict__ dinv,
                                                const int* __restrict__ rowstart,
                                                const int* __restrict__ winnode,
                                                const float* __restrict__ bias,
                                                const int* __restrict__ batch,
                                                float* __restrict__ pool,
                                                float* __restrict__ gsum,
                                                float* __restrict__ gsumsq) {
    int lane = threadIdx.x & 63;
    int wv = threadIdx.x >> 6;
    float bb = bias[lane];
    float s = 0.f, s2 = 0.f;
    __shared__ int anyw;
    if (threadIdx.x == 0) anyw = 0;
    __syncthreads();
    if (blockIdx.x < NWIN / 4) {
        int w = blockIdx.x * 4 + wv;
        int n = winnode[w];
        int rs = rowstart[n];
        if (w == rs / WIN + 1) {
            float di = dinv[n];
            float h = fmaxf((C[(size_t)n * DIM + lane]
                             + bfup(T[(size_t)n * DIM + lane])) * di + bb, 0.f);
            s += h; s2 += h * h;
            atomicAdd(&pool[(size_t)batch[n] * DIM + lane], h);
            anyw = 1;
        }
    } else {
        int base = (blockIdx.x - NWIN / 4) * 256 + wv * 64;
        int nb = base + lane;
        int d0 = 0;
        if (nb < N_NODES)
            d0 = (rowstart[nb + 1] == rowstart[nb]) && ((rowstart[nb] & (WIN - 1)) == 0);
        unsigned long long m = __ballot(d0);
        while (m) {
            int b = __builtin_ctzll(m);
            m &= m - 1;
            int n = base + b;
            float di = dinv[n];
            float h = fmaxf(bfup(T[(size_t)n * DIM + lane]) * di + bb, 0.f);
            s += h; s2 += h * h;
            atomicAdd(&pool[(size_t)batch[n] * DIM + lane], h);
            anyw = 1;
        }
    }
    __shared__ float ls[256], ls2[256];
    ls[threadIdx.x] = s; ls2[threadIdx.x] = s2;
    __syncthreads();
    if (anyw && threadIdx.x < 64) {
        int j = threadIdx.x;
        int slot = (blockIdx.x & (NSLOT - 1)) * DIM;
        atomicAdd(&gsum[slot + j],   ls[j] + ls[64 + j] + ls[128 + j] + ls[192 + j]);
        atomicAdd(&gsumsq[slot + j], ls2[j] + ls2[64 + j] + ls2[128 + j] + ls2[192 + j]);
    }
}

// ---------------- final: out[g] = ((pool/cnt)*scale + shift) @ Wout + bout --------------
__global__ void k_final(const float* __restrict__ pool, const int* __restrict__ start,
                        const float* __restrict__ scale, const float* __restrict__ shift,
                        const float* __restrict__ Wout, const float* __restrict__ bout,
                        float* __restrict__ out) {
    int g = blockIdx.x;
    int l = threadIdx.x;
    float c = fmaxf((float)(start[g + 1] - start[g]), 1.f);
    float p = (pool[g * DIM + l] / c) * scale[l] + shift[l];
    float a0 = p * Wout[l * 2 + 0];
    float a1 = p * Wout[l * 2 + 1];
    #pragma unroll
    for (int off = 32; off; off >>= 1) {
        a0 += __shfl_down(a0, off, 64);
        a1 += __shfl_down(a1, off, 64);
    }
    if (l == 0) {
        out[g * 2 + 0] = a0 + bout[0];
        out[g * 2 + 1] = a1 + bout[1];
    }
}

extern "C" void kernel_launch(void* const* d_in, const int* in_sizes, int n_in,
                              void* d_out, int out_size, void* d_ws, size_t ws_size,
                              hipStream_t stream) {
    (void)in_sizes; (void)n_in; (void)out_size; (void)ws_size;
    const float* x       = (const float*)d_in[0];
    const int*   ei      = (const int*)d_in[1];
    const int*   batch   = (const int*)d_in[2];
    const float* bn_in_g = (const float*)d_in[3];
    const float* bn_in_b = (const float*)d_in[4];
    const float* W1      = (const float*)d_in[5];
    const float* b1      = (const float*)d_in[6];
    const float* g1      = (const float*)d_in[7];
    const float* be1     = (const float*)d_in[8];
    const float* W2      = (const float*)d_in[9];
    const float* b2      = (const float*)d_in[10];
    const float* g2      = (const float*)d_in[11];
    const float* be2     = (const float*)d_in[12];
    const float* Wout    = (const float*)d_in[13];
    const float* bout    = (const float*)d_in[14];
    float* out = (float*)d_out;

    // workspace layout (~59 MB)
    char* p = (char*)d_ws;
    float* C = (float*)p;                   p += (size_t)N_NODES * DIM * 4;  // 25.6 MB
    unsigned short* H = (unsigned short*)p; p += (size_t)N_NODES * DIM * 2;  // 12.8 MB
    unsigned short* T = (unsigned short*)p; p += (size_t)N_NODES * DIM * 2;  // 12.8 MB
    int* csr = (int*)p;                     p += (size_t)N_EDGES * 4;        // 5.12 MB
    float* dinv = (float*)p;                p += N_NODES * 4;
    int* bh = (int*)p;                      p += NB * P1B * 4;
    int* iscan = (int*)p;                   p += NB * P1B * 4;
    int* rowstart = (int*)p;                p += (N_NODES + 2) * 4;
    int* winnode = (int*)p;                 p += NWIN * 4;
    int* bsum = (int*)p;                    p += NB * 4;
    int* boff = (int*)p;                    p += NB * 4;
    int* start = (int*)p;                   p += (N_GRAPHS + 2) * 4;
    float* gsum = (float*)p;                p += NSLOT * DIM * 4;
    float* gsumsq = (float*)p;              p += NSLOT * DIM * 4;
    float* scale = (float*)p;               p += DIM * 4;
    float* shift = (float*)p;               p += DIM * 4;
    float* cshift = (float*)p;              p += DIM * 4;
    float* pool = (float*)p;                p += (size_t)N_GRAPHS * DIM * 4;
    int2* tmp = (int2*)H;  // bucket-sort temp aliases H (dead before k_gather1 writes H)

    // ---- CSR build (LDS bucket sort) + BN-input stats + graph boundaries ----
    hipMemsetAsync(gsum, 0, 2 * NSLOT * DIM * sizeof(float), stream);
    hipMemsetAsync(pool, 0, (size_t)N_GRAPHS * DIM * sizeof(float), stream);
    k_p1hist<<<P1B + SB + 392, 256, 0, stream>>>(ei, batch, x, bh, start, gsum, gsumsq);
    k_scan1<<<NB, 256, 0, stream>>>(bh, iscan, bsum);
    k_scan2<<<1, 512, 0, stream>>>(bsum, boff);
    k_p1scat<<<P1B, 256, 0, stream>>>(ei, bh, iscan, boff, tmp);
    k_p2a<<<NB, 256, 0, stream>>>(tmp, bh, iscan, boff, rowstart, dinv, winnode);
    k_p2b<<<NB, 256, 0, stream>>>(tmp, bh, iscan, boff, rowstart, csr);

    // ---- input BN -> GEMM1 (T'=T*dinv) -> gather1 (fused relu+H+stats) -> straddle ----
    k_bnfold<<<1, 64, 0, stream>>>(gsum, gsumsq, bn_in_g, bn_in_b, W1, scale, cshift);
    k_gemm_f32<<<(N_NODES + 63) / 64, 256, 0, stream>>>(x, W1, scale, cshift, dinv, T);
    k_zstrad<<<NWIN / 4, 256, 0, stream>>>(rowstart, winnode, C);
    k_gather1<<<NWIN / 4, 256, 0, stream>>>(T, dinv, rowstart, winnode, csr, b1,
                                            C, H, gsum, gsumsq);
    k_strad1<<<NWIN / 4 + 392, 256, 0, stream>>>(C, T, dinv, rowstart, winnode, b1,
                                                 H, gsum, gsumsq);

    // ---- BN1 -> GEMM2 (bf16 A) -> gather2 (fused relu+pool+stats) -> straddle ----
    k_bnfold<<<1, 64, 0, stream>>>(gsum, gsumsq, g1, be1, W2, scale, cshift);
    k_gemm_b16<<<(N_NODES + 63) / 64, 256, 0, stream>>>(H, W2, scale, cshift, dinv, T);
    k_zstrad<<<NWIN / 4, 256, 0, stream>>>(rowstart, winnode, C);
    k_gather2<<<NWIN / 4, 256, 0, stream>>>(T, dinv, rowstart, winnode, csr, b2,
                                            batch, C, pool, gsum, gsumsq);
    k_strad2<<<NWIN / 4 + 392, 256, 0, stream>>>(C, T, dinv, rowstart, winnode, b2,
                                                 batch, pool, gsum, gsumsq);

    // ---- BN2 (post-pool; BN affine, pool linear) -> linear ----
    k_bnfinal<<<1, 64, 0, stream>>>(gsum, gsumsq, g2, be2, scale, shift);
    k_final<<<N_GRAPHS, 64, 0, stream>>>(pool, start, scale, shift, Wout, bout, out);
}

// Round 14
// 330.397 us; speedup vs baseline: 1.0245x; 1.0245x over previous
//
#include <hip/hip_runtime.h>
#include <math.h>

#define N_NODES 100000
#define N_EDGES 1280000
#define DIM 64
#define N_GRAPHS 1000
#define BN_EPS 1e-5f
#define NB 392            // buckets = dst>>8; 392*256 = 100352 >= N_NODES
#define P1B 256           // pass-1 histogram blocks; 256*5000 = 1.28M exactly
#define P1E 5000
#define SB 400            // stats blocks (400*250 = 100k rows, contiguous spans)
#define WIN 128           // edges per gather wave window; N_EDGES/WIN = 10000
#define NWIN (N_EDGES / WIN)
#define GU 8              // edge unroll (R12-verified; GU=16 was neutral)
#define NSLOT 32          // BN-stat partial slots

// ---- bf16 helpers (top 16 bits of fp32, RTN) ----
__device__ __forceinline__ unsigned int bf16_rtn2(float a, float b) {
    unsigned int ua = __float_as_uint(a);
    unsigned int ub = __float_as_uint(b);
    ua = (ua + 0x7FFFu + ((ua >> 16) & 1u)) >> 16;
    ub = (ub + 0x7FFFu + ((ub >> 16) & 1u)) >> 16;
    return ua | (ub << 16);
}
__device__ __forceinline__ unsigned short bf16r(float a) {
    unsigned int u = __float_as_uint(a);
    return (unsigned short)((u + 0x7FFFu + ((u >> 16) & 1u)) >> 16);
}
__device__ __forceinline__ float bfup(unsigned short u) {
    return __uint_as_float(((unsigned int)u) << 16);
}

// ---------------- pass 1a: bucket histogram + BN-input stats + graph boundaries ---------
__global__ __launch_bounds__(256) void k_p1hist(const int* __restrict__ ei,
                                                const int* __restrict__ batch,
                                                const float* __restrict__ X,
                                                int* __restrict__ bh,
                                                int* __restrict__ start,
                                                float* __restrict__ gsum,
                                                float* __restrict__ gsumsq) {
    int t = threadIdx.x;
    if (blockIdx.x < P1B) {
        __shared__ int hist[NB];
        for (int b = t; b < NB; b += 256) hist[b] = 0;
        __syncthreads();
        int e0 = blockIdx.x * P1E;
        #pragma unroll 4
        for (int e = e0 + t; e < e0 + P1E; e += 256)
            atomicAdd(&hist[ei[N_EDGES + e] >> 8], 1);
        __syncthreads();
        for (int b = t; b < NB; b += 256) bh[b * P1B + blockIdx.x] = hist[b];
    } else if (blockIdx.x < P1B + SB) {
        int grp = blockIdx.x - P1B;
        int j = t & 63, rg = t >> 6;
        int base = grp * 250;
        float s = 0.f, s2 = 0.f;
        for (int i = base + rg; i < base + 250; i += 4) {
            float v = X[i * DIM + j];
            s += v; s2 += v * v;
        }
        __shared__ float ls[256], ls2[256];
        ls[t] = s; ls2[t] = s2;
        __syncthreads();
        if (t < 64) {
            int slot = (grp & (NSLOT - 1)) * DIM;
            s  = ls[j]  + ls[64 + j]  + ls[128 + j]  + ls[192 + j];
            s2 = ls2[j] + ls2[64 + j] + ls2[128 + j] + ls2[192 + j];
            atomicAdd(&gsum[slot + j], s);
            atomicAdd(&gsumsq[slot + j], s2);
        }
    } else {
        int i = (blockIdx.x - P1B - SB) * 256 + t;
        if (i < N_NODES) {
            int cur = batch[i];
            if (i == 0) { for (int q = 0; q <= cur; q++) start[q] = 0; }
            else {
                int prev = batch[i - 1];
                for (int q = prev + 1; q <= cur; q++) start[q] = i;
            }
            if (i == N_NODES - 1)
                for (int q = cur + 1; q <= N_GRAPHS; q++) start[q] = N_NODES;
        }
    }
}

// ---------------- scan of bh[100352] ----------------
__global__ void k_scan1(const int* __restrict__ bh, int* __restrict__ iscan,
                        int* __restrict__ bsum) {
    __shared__ int ls[256];
    int i = blockIdx.x * 256 + threadIdx.x;
    int v = bh[i];
    ls[threadIdx.x] = v;
    __syncthreads();
    for (int off = 1; off < 256; off <<= 1) {
        int tv = (threadIdx.x >= off) ? ls[threadIdx.x - off] : 0;
        __syncthreads();
        ls[threadIdx.x] += tv;
        __syncthreads();
    }
    iscan[i] = ls[threadIdx.x];
    if (threadIdx.x == 255) bsum[blockIdx.x] = ls[255];
}

__global__ void k_scan2(const int* __restrict__ bsum, int* __restrict__ boff) {
    __shared__ int ls[512];
    int t = threadIdx.x;
    int v0 = (t < NB) ? bsum[t] : 0;
    ls[t] = v0;
    __syncthreads();
    for (int off = 1; off < 512; off <<= 1) {
        int v = (t >= off) ? ls[t - off] : 0;
        __syncthreads();
        ls[t] += v;
        __syncthreads();
    }
    if (t < NB) boff[t] = ls[t] - v0;
}

// ---------------- pass 1b: scatter packed {src<<8|dstlow} into bucket-major tmp ---------
__global__ __launch_bounds__(256) void k_p1scat(const int* __restrict__ ei,
                                                const int* __restrict__ bh,
                                                const int* __restrict__ iscan,
                                                const int* __restrict__ boff,
                                                int* __restrict__ tmp) {
    __shared__ int cur[NB];
    int blk = blockIdx.x;
    for (int b = threadIdx.x; b < NB; b += 256) {
        int i = b * P1B + blk;
        cur[b] = boff[b] + iscan[i] - bh[i];
    }
    __syncthreads();
    int e0 = blk * P1E;
    for (int e = e0 + threadIdx.x; e < e0 + P1E; e += 256) {
        int r = ei[e], c = ei[N_EDGES + e];
        int pos = atomicAdd(&cur[c >> 8], 1);
        tmp[pos] = (r << 8) | (c & 255);
    }
}

// ---------------- pass 2a: per-bucket histogram -> dinv, rowstart, winnode --------------
// Also zeros C rows of straddler nodes (replaces k_zstrad for layer 1).
__global__ __launch_bounds__(256) void k_p2a(const int* __restrict__ tmp,
                                             const int* __restrict__ bh,
                                             const int* __restrict__ iscan,
                                             const int* __restrict__ boff,
                                             int* __restrict__ rowstart,
                                             float* __restrict__ dinv,
                                             int* __restrict__ winnode,
                                             float* __restrict__ C) {
    int b = blockIdx.x, t = threadIdx.x;
    int bstart = boff[b] + iscan[b * 256] - bh[b * 256];
    int bend = (b == NB - 1) ? N_EDGES
                             : (boff[b + 1] + iscan[(b + 1) * 256] - bh[(b + 1) * 256]);
    __shared__ int cnt[256], scn[256];
    cnt[t] = 0;
    __syncthreads();
    for (int e = bstart + t; e < bend; e += 256)
        atomicAdd(&cnt[tmp[e] & 255], 1);
    __syncthreads();
    scn[t] = cnt[t];
    __syncthreads();
    for (int off = 1; off < 256; off <<= 1) {
        int v = (t >= off) ? scn[t - off] : 0;
        __syncthreads();
        scn[t] += v;
        __syncthreads();
    }
    int node = b * 256 + t;
    int deg = cnt[t];
    int rs = bstart + scn[t] - deg;
    bool span = false;
    if (node <= N_NODES) rowstart[node] = rs;
    if (node < N_NODES) {
        dinv[node] = 1.0f / sqrtf((float)(deg + 1));
        int re = rs + deg;
        for (int w = (rs + WIN - 1) / WIN; w * WIN < re; ++w) winnode[w] = node;
        span = (deg > 0) && (rs / WIN != (re - 1) / WIN);
    }
    // zero C rows of straddler nodes (wave-cooperative: 64 lanes write one row)
    int lane = t & 63;
    int wbase = b * 256 + (t & ~63);
    unsigned long long m = __ballot(span);
    while (m) {
        int bit = __builtin_ctzll(m);
        m &= m - 1;
        C[(size_t)(wbase + bit) * DIM + lane] = 0.f;
    }
}

// ---------------- pass 2b: within-bucket sort -> final CSR (src only) ----------------
__global__ __launch_bounds__(256) void k_p2b(const int* __restrict__ tmp,
                                             const int* __restrict__ bh,
                                             const int* __restrict__ iscan,
                                             const int* __restrict__ boff,
                                             const int* __restrict__ rowstart,
                                             int* __restrict__ csr) {
    int b = blockIdx.x, t = threadIdx.x;
    int bstart = boff[b] + iscan[b * 256] - bh[b * 256];
    int bend = (b == NB - 1) ? N_EDGES
                             : (boff[b + 1] + iscan[(b + 1) * 256] - bh[(b + 1) * 256]);
    __shared__ int curs[256];
    int node = b * 256 + t;
    curs[t] = (node < N_NODES) ? rowstart[node] : 0;
    __syncthreads();
    for (int e = bstart + t; e < bend; e += 256) {
        int rec = tmp[e];
        int pos = atomicAdd(&curs[rec & 255], 1);
        csr[pos] = (int)((unsigned)rec >> 8);
    }
}

// ---------------- BN fold: reduce 32 slots, scale/cshift, re-zero slots ----------------
__global__ void k_bnfold(float* __restrict__ gsum, float* __restrict__ gsumsq,
                         const float* __restrict__ g, const float* __restrict__ b,
                         const float* __restrict__ W,
                         float* __restrict__ scale, float* __restrict__ cshift) {
    int j = threadIdx.x;
    float ms = 0.f, m2 = 0.f;
    for (int k = 0; k < NSLOT; k++) {
        ms += gsum[k * DIM + j];   gsum[k * DIM + j] = 0.f;
        m2 += gsumsq[k * DIM + j]; gsumsq[k * DIM + j] = 0.f;
    }
    float mean = ms * (1.0f / N_NODES);
    float var  = m2 * (1.0f / N_NODES) - mean * mean;
    float inv  = 1.0f / sqrtf(var + BN_EPS);
    float sc   = g[j] * inv;
    scale[j] = sc;
    __shared__ float shl[64];
    shl[j] = b[j] - mean * sc;
    __syncthreads();
    float s = 0.f;
    for (int k = 0; k < DIM; k++) s += shl[k] * W[k * DIM + j];
    cshift[j] = s;
}

__global__ void k_bnfinal(const float* __restrict__ gsum, const float* __restrict__ gsumsq,
                          const float* __restrict__ g, const float* __restrict__ b,
                          float* __restrict__ scale, float* __restrict__ shift) {
    int j = threadIdx.x;
    float ms = 0.f, m2 = 0.f;
    for (int k = 0; k < NSLOT; k++) { ms += gsum[k * DIM + j]; m2 += gsumsq[k * DIM + j]; }
    float mean = ms * (1.0f / N_NODES);
    float var  = m2 * (1.0f / N_NODES) - mean * mean;
    float inv  = 1.0f / sqrtf(var + BN_EPS);
    float sc   = g[j] * inv;
    scale[j] = sc;
    shift[j] = b[j] - mean * sc;
}

// ---------------- GEMM (fp32 A): T' = ((X*scale)@W + cshift)*dinv[row], bf16 ------------
__global__ __launch_bounds__(256) void k_gemm_f32(const float* __restrict__ X,
                                                  const float* __restrict__ W,
                                                  const float* __restrict__ scale,
                                                  const float* __restrict__ cshift,
                                                  const float* __restrict__ dinv,
                                                  unsigned short* __restrict__ T) {
    __shared__ float Wl[64 * 64];
    __shared__ float Al[64 * 65];
    for (int t = threadIdx.x; t < 4096; t += 256) Wl[t] = W[t] * scale[t >> 6];
    int row0 = blockIdx.x * 64;
    for (int t = threadIdx.x; t < 4096; t += 256) {
        int r = t >> 6, k = t & 63;
        int i = row0 + r;
        Al[r * 65 + k] = (i < N_NODES) ? X[(size_t)i * DIM + k] : 0.f;
    }
    __syncthreads();
    int r = threadIdx.x & 63;
    int q = threadIdx.x >> 6;
    float acc[16];
    #pragma unroll
    for (int jj = 0; jj < 16; jj++) acc[jj] = cshift[q * 16 + jj];
    #pragma unroll 4
    for (int k = 0; k < 64; k++) {
        float a = Al[r * 65 + k];
        const float4* wv = (const float4*)&Wl[k * 64 + q * 16];
        float4 w0 = wv[0], w1 = wv[1], w2 = wv[2], w3 = wv[3];
        acc[0]  += a * w0.x; acc[1]  += a * w0.y; acc[2]  += a * w0.z; acc[3]  += a * w0.w;
        acc[4]  += a * w1.x; acc[5]  += a * w1.y; acc[6]  += a * w1.z; acc[7]  += a * w1.w;
        acc[8]  += a * w2.x; acc[9]  += a * w2.y; acc[10] += a * w2.z; acc[11] += a * w2.w;
        acc[12] += a * w3.x; acc[13] += a * w3.y; acc[14] += a * w3.z; acc[15] += a * w3.w;
    }
    int i = row0 + r;
    if (i < N_NODES) {
        float dv = dinv[i];
        unsigned int pk[8];
        #pragma unroll
        for (int jj = 0; jj < 8; jj++)
            pk[jj] = bf16_rtn2(acc[2 * jj] * dv, acc[2 * jj + 1] * dv);
        uint4* outv = (uint4*)&T[(size_t)i * DIM + q * 16];
        outv[0] = make_uint4(pk[0], pk[1], pk[2], pk[3]);
        outv[1] = make_uint4(pk[4], pk[5], pk[6], pk[7]);
    }
}

// ---------------- GEMM (bf16 A): T' = ((H*scale)@W + cshift)*dinv[row], bf16 ------------
__global__ __launch_bounds__(256) void k_gemm_b16(const unsigned short* __restrict__ X,
                                                  const float* __restrict__ W,
                                                  const float* __restrict__ scale,
                                                  const float* __restrict__ cshift,
                                                  const float* __restrict__ dinv,
                                                  unsigned short* __restrict__ T) {
    __shared__ float Wl[64 * 64];
    __shared__ float Al[64 * 65];
    for (int t = threadIdx.x; t < 4096; t += 256) Wl[t] = W[t] * scale[t >> 6];
    int row0 = blockIdx.x * 64;
    for (int t = threadIdx.x; t < 4096; t += 256) {
        int r = t >> 6, k = t & 63;
        int i = row0 + r;
        Al[r * 65 + k] = (i < N_NODES) ? bfup(X[(size_t)i * DIM + k]) : 0.f;
    }
    __syncthreads();
    int r = threadIdx.x & 63;
    int q = threadIdx.x >> 6;
    float acc[16];
    #pragma unroll
    for (int jj = 0; jj < 16; jj++) acc[jj] = cshift[q * 16 + jj];
    #pragma unroll 4
    for (int k = 0; k < 64; k++) {
        float a = Al[r * 65 + k];
        const float4* wv = (const float4*)&Wl[k * 64 + q * 16];
        float4 w0 = wv[0], w1 = wv[1], w2 = wv[2], w3 = wv[3];
        acc[0]  += a * w0.x; acc[1]  += a * w0.y; acc[2]  += a * w0.z; acc[3]  += a * w0.w;
        acc[4]  += a * w1.x; acc[5]  += a * w1.y; acc[6]  += a * w1.z; acc[7]  += a * w1.w;
        acc[8]  += a * w2.x; acc[9]  += a * w2.y; acc[10] += a * w2.z; acc[11] += a * w2.w;
        acc[12] += a * w3.x; acc[13] += a * w3.y; acc[14] += a * w3.z; acc[15] += a * w3.w;
    }
    int i = row0 + r;
    if (i < N_NODES) {
        float dv = dinv[i];
        unsigned int pk[8];
        #pragma unroll
        for (int jj = 0; jj < 8; jj++)
            pk[jj] = bf16_rtn2(acc[2 * jj] * dv, acc[2 * jj + 1] * dv);
        uint4* outv = (uint4*)&T[(size_t)i * DIM + q * 16];
        outv[0] = make_uint4(pk[0], pk[1], pk[2], pk[3]);
        outv[1] = make_uint4(pk[4], pk[5], pk[6], pk[7]);
    }
}

// ---------------- gather layer 1: h = relu((Σ T'[src] + T'[i])·dinv[i] + bias) ----------
__global__ __launch_bounds__(256) void k_gather1(const unsigned short* __restrict__ T,
                                                 const float* __restrict__ dinv,
                                                 const int* __restrict__ rowstart,
                                                 const int* __restrict__ winnode,
                                                 const int* __restrict__ csr,
                                                 const float* __restrict__ bias,
                                                 float* __restrict__ C,
                                                 unsigned short* __restrict__ H,
                                                 float* __restrict__ gsum,
                                                 float* __restrict__ gsumsq) {
    int lane = threadIdx.x & 63;
    int w = blockIdx.x * 4 + (threadIdx.x >> 6);
    float bb = bias[lane];
    float s = 0.f, s2 = 0.f;
    int e = w * WIN;
    const int eend = e + WIN;
    int i  = __builtin_amdgcn_readfirstlane(winnode[w]);
    int re = __builtin_amdgcn_readfirstlane(rowstart[i + 1]);
    bool part = __builtin_amdgcn_readfirstlane(rowstart[i]) < e;
    float acc = 0.f;
    for (; e < eend; e += GU) {
        int src[GU];
        int eu = __builtin_amdgcn_readfirstlane(e);
        #pragma unroll
        for (int u = 0; u < GU; u++) src[u] = csr[eu + u];
        float tv[GU];
        #pragma unroll
        for (int u = 0; u < GU; u++) tv[u] = bfup(T[(size_t)src[u] * DIM + lane]);
        #pragma unroll
        for (int u = 0; u < GU; u++) {
            while (e + u == re) {
                if (part) { atomicAdd(&C[(size_t)i * DIM + lane], acc); part = false; }
                else {
                    float di = dinv[i];
                    float h = fmaxf((acc + bfup(T[(size_t)i * DIM + lane])) * di + bb, 0.f);
                    H[(size_t)i * DIM + lane] = bf16r(h);
                    s += h; s2 += h * h;
                }
                acc = 0.f; ++i;
                re = __builtin_amdgcn_readfirstlane(rowstart[i + 1]);
            }
            acc += tv[u];
        }
    }
    if (part || re > eend) atomicAdd(&C[(size_t)i * DIM + lane], acc);
    else {
        float di = dinv[i];
        float h = fmaxf((acc + bfup(T[(size_t)i * DIM + lane])) * di + bb, 0.f);
        H[(size_t)i * DIM + lane] = bf16r(h);
        s += h; s2 += h * h;
    }
    __shared__ float ls[256], ls2[256];
    ls[threadIdx.x] = s; ls2[threadIdx.x] = s2;
    __syncthreads();
    if (threadIdx.x < 64) {
        int j = threadIdx.x;
        int slot = (blockIdx.x & (NSLOT - 1)) * DIM;
        atomicAdd(&gsum[slot + j],   ls[j] + ls[64 + j] + ls[128 + j] + ls[192 + j]);
        atomicAdd(&gsumsq[slot + j], ls2[j] + ls2[64 + j] + ls2[128 + j] + ls2[192 + j]);
    }
}

// ---------------- gather layer 2: h -> pool(run-flush) + stats ----------------
__global__ __launch_bounds__(256) void k_gather2(const unsigned short* __restrict__ T,
                                                 const float* __restrict__ dinv,
                                                 const int* __restrict__ rowstart,
                                                 const int* __restrict__ winnode,
                                                 const int* __restrict__ csr,
                                                 const float* __restrict__ bias,
                                                 const int* __restrict__ batch,
                                                 float* __restrict__ C,
                                                 float* __restrict__ pool,
                                                 float* __restrict__ gsum,
                                                 float* __restrict__ gsumsq) {
    int lane = threadIdx.x & 63;
    int w = blockIdx.x * 4 + (threadIdx.x >> 6);
    float bb = bias[lane];
    float s = 0.f, s2 = 0.f, ps = 0.f;
    int cur_g = -1;
    int e = w * WIN;
    const int eend = e + WIN;
    int i  = __builtin_amdgcn_readfirstlane(winnode[w]);
    int re = __builtin_amdgcn_readfirstlane(rowstart[i + 1]);
    bool part = __builtin_amdgcn_readfirstlane(rowstart[i]) < e;
    float acc = 0.f;
    for (; e < eend; e += GU) {
        int src[GU];
        int eu = __builtin_amdgcn_readfirstlane(e);
        #pragma unroll
        for (int u = 0; u < GU; u++) src[u] = csr[eu + u];
        float tv[GU];
        #pragma unroll
        for (int u = 0; u < GU; u++) tv[u] = bfup(T[(size_t)src[u] * DIM + lane]);
        #pragma unroll
        for (int u = 0; u < GU; u++) {
            while (e + u == re) {
                if (part) { atomicAdd(&C[(size_t)i * DIM + lane], acc); part = false; }
                else {
                    float di = dinv[i];
                    float h = fmaxf((acc + bfup(T[(size_t)i * DIM + lane])) * di + bb, 0.f);
                    s += h; s2 += h * h;
                    int g = batch[i];
                    if (g != cur_g) {
                        if (cur_g >= 0) atomicAdd(&pool[(size_t)cur_g * DIM + lane], ps);
                        ps = 0.f; cur_g = g;
                    }
                    ps += h;
                }
                acc = 0.f; ++i;
                re = __builtin_amdgcn_readfirstlane(rowstart[i + 1]);
            }
            acc += tv[u];
        }
    }
    if (part || re > eend) atomicAdd(&C[(size_t)i * DIM + lane], acc);
    else {
        float di = dinv[i];
        float h = fmaxf((acc + bfup(T[(size_t)i * DIM + lane])) * di + bb, 0.f);
        s += h; s2 += h * h;
        int g = batch[i];
        if (g != cur_g) {
            if (cur_g >= 0) atomicAdd(&pool[(size_t)cur_g * DIM + lane], ps);
            ps = 0.f; cur_g = g;
        }
        ps += h;
    }
    if (cur_g >= 0) atomicAdd(&pool[(size_t)cur_g * DIM + lane], ps);
    __shared__ float ls[256], ls2[256];
    ls[threadIdx.x] = s; ls2[threadIdx.x] = s2;
    __syncthreads();
    if (threadIdx.x < 64) {
        int j = threadIdx.x;
        int slot = (blockIdx.x & (NSLOT - 1)) * DIM;
        atomicAdd(&gsum[slot + j],   ls[j] + ls[64 + j] + ls[128 + j] + ls[192 + j]);
        atomicAdd(&gsumsq[slot + j], ls2[j] + ls2[64 + j] + ls2[128 + j] + ls2[192 + j]);
    }
}

// ---------------- straddler + boundary-deg0 finish, layer 1 (-> H + stats) --------------
// Owner-window role also re-zeros C[n] after reading (prepares layer 2; replaces zstrad2).
__global__ __launch_bounds__(256) void k_strad1(float* __restrict__ C,
                                                const unsigned short* __restrict__ T,
                                                const float* __restrict__ dinv,
                                                const int* __restrict__ rowstart,
                                                const int* __restrict__ winnode,
                                                const float* __restrict__ bias,
                                                unsigned short* __restrict__ H,
                                                float* __restrict__ gsum,
                                                float* __restrict__ gsumsq) {
    int lane = threadIdx.x & 63;
    int wv = threadIdx.x >> 6;
    float bb = bias[lane];
    float s = 0.f, s2 = 0.f;
    __shared__ int anyw;
    if (threadIdx.x == 0) anyw = 0;
    __syncthreads();
    if (blockIdx.x < NWIN / 4) {
        int w = blockIdx.x * 4 + wv;
        int n = winnode[w];
        int rs = rowstart[n];
        if (w == rs / WIN + 1) {
            float di = dinv[n];
            float c = C[(size_t)n * DIM + lane];
            C[(size_t)n * DIM + lane] = 0.f;        // re-zero for layer 2
            float h = fmaxf((c + bfup(T[(size_t)n * DIM + lane])) * di + bb, 0.f);
            H[(size_t)n * DIM + lane] = bf16r(h);
            s += h; s2 += h * h;
            anyw = 1;
        }
    } else {
        int base = (blockIdx.x - NWIN / 4) * 256 + wv * 64;
        int nb = base + lane;
        int d0 = 0;
        if (nb < N_NODES)
            d0 = (rowstart[nb + 1] == rowstart[nb]) && ((rowstart[nb] & (WIN - 1)) == 0);
        unsigned long long m = __ballot(d0);
        while (m) {
            int b = __builtin_ctzll(m);
            m &= m - 1;
            int n = base + b;
            float di = dinv[n];
            float h = fmaxf(bfup(T[(size_t)n * DIM + lane]) * di + bb, 0.f);
            H[(size_t)n * DIM + lane] = bf16r(h);
            s += h; s2 += h * h;
            anyw = 1;
        }
    }
    __shared__ float ls[256], ls2[256];
    ls[threadIdx.x] = s; ls2[threadIdx.x] = s2;
    __syncthreads();
    if (anyw && threadIdx.x < 64) {
        int j = threadIdx.x;
        int slot = (blockIdx.x & (NSLOT - 1)) * DIM;
        atomicAdd(&gsum[slot + j],   ls[j] + ls[64 + j] + ls[128 + j] + ls[192 + j]);
        atomicAdd(&gsumsq[slot + j], ls2[j] + ls2[64 + j] + ls2[128 + j] + ls2[192 + j]);
    }
}

// ---------------- straddler + boundary-deg0 finish, layer 2 (-> pool + stats) -----------
__global__ __launch_bounds__(256) void k_strad2(const float* __restrict__ C,
                                                const unsigned short* __restrict__ T,
                                                const float* __restrict__ dinv,
                                                const int* __restrict__ rowstart,
                                                const int* __restrict__ winnode,
                                                const float* __restrict__ bias,
                                                const int* __restrict__ batch,
                                                float* __restrict__ pool,
                                                float* __restrict__ gsum,
                                                float* __restrict__ gsumsq) {
    int lane = threadIdx.x & 63;
    int wv = threadIdx.x >> 6;
    float bb = bias[lane];
    float s = 0.f, s2 = 0.f;
    __shared__ int anyw;
    if (threadIdx.x == 0) anyw = 0;
    __syncthreads();
    if (blockIdx.x < NWIN / 4) {
        int w = blockIdx.x * 4 + wv;
        int n = winnode[w];
        int rs = rowstart[n];
        if (w == rs / WIN + 1) {
            float di = dinv[n];
            float h = fmaxf((C[(size_t)n * DIM + lane]
                             + bfup(T[(size_t)n * DIM + lane])) * di + bb, 0.f);
            s += h; s2 += h * h;
            atomicAdd(&pool[(size_t)batch[n] * DIM + lane], h);
            anyw = 1;
        }
    } else {
        int base = (blockIdx.x - NWIN / 4) * 256 + wv * 64;
        int nb = base + lane;
        int d0 = 0;
        if (nb < N_NODES)
            d0 = (rowstart[nb + 1] == rowstart[nb]) && ((rowstart[nb] & (WIN - 1)) == 0);
        unsigned long long m = __ballot(d0);
        while (m) {
            int b = __builtin_ctzll(m);
            m &= m - 1;
            int n = base + b;
            float di = dinv[n];
            float h = fmaxf(bfup(T[(size_t)n * DIM + lane]) * di + bb, 0.f);
            s += h; s2 += h * h;
            atomicAdd(&pool[(size_t)batch[n] * DIM + lane], h);
            anyw = 1;
        }
    }
    __shared__ float ls[256], ls2[256];
    ls[threadIdx.x] = s; ls2[threadIdx.x] = s2;
    __syncthreads();
    if (anyw && threadIdx.x < 64) {
        int j = threadIdx.x;
        int slot = (blockIdx.x & (NSLOT - 1)) * DIM;
        atomicAdd(&gsum[slot + j],   ls[j] + ls[64 + j] + ls[128 + j] + ls[192 + j]);
        atomicAdd(&gsumsq[slot + j], ls2[j] + ls2[64 + j] + ls2[128 + j] + ls2[192 + j]);
    }
}

// ---------------- final: out[g] = ((pool/cnt)*scale + shift) @ Wout + bout --------------
__global__ void k_final(const float* __restrict__ pool, const int* __restrict__ start,
                        const float* __restrict__ scale, const float* __restrict__ shift,
                        const float* __restrict__ Wout, const float* __restrict__ bout,
                        float* __restrict__ out) {
    int g = blockIdx.x;
    int l = threadIdx.x;
    float c = fmaxf((float)(start[g + 1] - start[g]), 1.f);
    float p = (pool[g * DIM + l] / c) * scale[l] + shift[l];
    float a0 = p * Wout[l * 2 + 0];
    float a1 = p * Wout[l * 2 + 1];
    #pragma unroll
    for (int off = 32; off; off >>= 1) {
        a0 += __shfl_down(a0, off, 64);
        a1 += __shfl_down(a1, off, 64);
    }
    if (l == 0) {
        out[g * 2 + 0] = a0 + bout[0];
        out[g * 2 + 1] = a1 + bout[1];
    }
}

extern "C" void kernel_launch(void* const* d_in, const int* in_sizes, int n_in,
                              void* d_out, int out_size, void* d_ws, size_t ws_size,
                              hipStream_t stream) {
    (void)in_sizes; (void)n_in; (void)out_size; (void)ws_size;
    const float* x       = (const float*)d_in[0];
    const int*   ei      = (const int*)d_in[1];
    const int*   batch   = (const int*)d_in[2];
    const float* bn_in_g = (const float*)d_in[3];
    const float* bn_in_b = (const float*)d_in[4];
    const float* W1      = (const float*)d_in[5];
    const float* b1      = (const float*)d_in[6];
    const float* g1      = (const float*)d_in[7];
    const float* be1     = (const float*)d_in[8];
    const float* W2      = (const float*)d_in[9];
    const float* b2      = (const float*)d_in[10];
    const float* g2      = (const float*)d_in[11];
    const float* be2     = (const float*)d_in[12];
    const float* Wout    = (const float*)d_in[13];
    const float* bout    = (const float*)d_in[14];
    float* out = (float*)d_out;

    // workspace layout (~59 MB)
    char* p = (char*)d_ws;
    float* C = (float*)p;                   p += (size_t)N_NODES * DIM * 4;  // 25.6 MB
    unsigned short* H = (unsigned short*)p; p += (size_t)N_NODES * DIM * 2;  // 12.8 MB
    unsigned short* T = (unsigned short*)p; p += (size_t)N_NODES * DIM * 2;  // 12.8 MB
    int* csr = (int*)p;                     p += (size_t)N_EDGES * 4;        // 5.12 MB
    float* dinv = (float*)p;                p += N_NODES * 4;
    int* bh = (int*)p;                      p += NB * P1B * 4;
    int* iscan = (int*)p;                   p += NB * P1B * 4;
    int* rowstart = (int*)p;                p += (N_NODES + 2) * 4;
    int* winnode = (int*)p;                 p += NWIN * 4;
    int* bsum = (int*)p;                    p += NB * 4;
    int* boff = (int*)p;                    p += NB * 4;
    int* start = (int*)p;                   p += (N_GRAPHS + 2) * 4;
    float* gsum = (float*)p;                p += NSLOT * DIM * 4;
    float* gsumsq = (float*)p;              p += NSLOT * DIM * 4;
    float* scale = (float*)p;               p += DIM * 4;
    float* shift = (float*)p;               p += DIM * 4;
    float* cshift = (float*)p;              p += DIM * 4;
    float* pool = (float*)p;                p += (size_t)N_GRAPHS * DIM * 4;
    int* tmp = (int*)H;   // packed bucket-sort temp aliases H (dead before gather1 writes H)

    // ---- CSR build (LDS bucket sort) + BN-input stats + graph boundaries ----
    hipMemsetAsync(gsum, 0, 2 * NSLOT * DIM * sizeof(float), stream);
    hipMemsetAsync(pool, 0, (size_t)N_GRAPHS * DIM * sizeof(float), stream);
    k_p1hist<<<P1B + SB + 392, 256, 0, stream>>>(ei, batch, x, bh, start, gsum, gsumsq);
    k_scan1<<<NB, 256, 0, stream>>>(bh, iscan, bsum);
    k_scan2<<<1, 512, 0, stream>>>(bsum, boff);
    k_p1scat<<<P1B, 256, 0, stream>>>(ei, bh, iscan, boff, tmp);
    k_p2a<<<NB, 256, 0, stream>>>(tmp, bh, iscan, boff, rowstart, dinv, winnode, C);
    k_p2b<<<NB, 256, 0, stream>>>(tmp, bh, iscan, boff, rowstart, csr);

    // ---- input BN -> GEMM1 (T'=T*dinv) -> gather1 (fused relu+H+stats) -> straddle ----
    k_bnfold<<<1, 64, 0, stream>>>(gsum, gsumsq, bn_in_g, bn_in_b, W1, scale, cshift);
    k_gemm_f32<<<(N_NODES + 63) / 64, 256, 0, stream>>>(x, W1, scale, cshift, dinv, T);
    k_gather1<<<NWIN / 4, 256, 0, stream>>>(T, dinv, rowstart, winnode, csr, b1,
                                            C, H, gsum, gsumsq);
    k_strad1<<<NWIN / 4 + 392, 256, 0, stream>>>(C, T, dinv, rowstart, winnode, b1,
                                                 H, gsum, gsumsq);

    // ---- BN1 -> GEMM2 (bf16 A) -> gather2 (fused relu+pool+stats) -> straddle ----
    k_bnfold<<<1, 64, 0, stream>>>(gsum, gsumsq, g1, be1, W2, scale, cshift);
    k_gemm_b16<<<(N_NODES + 63) / 64, 256, 0, stream>>>(H, W2, scale, cshift, dinv, T);
    k_gather2<<<NWIN / 4, 256, 0, stream>>>(T, dinv, rowstart, winnode, csr, b2,
                                            batch, C, pool, gsum, gsumsq);
    k_strad2<<<NWIN / 4 + 392, 256, 0, stream>>>(C, T, dinv, rowstart, winnode, b2,
                                                 batch, pool, gsum, gsumsq);

    // ---- BN2 (post-pool; BN affine, pool linear) -> linear ----
    k_bnfinal<<<1, 64, 0, stream>>>(gsum, gsumsq, g2, be2, scale, shift);
    k_final<<<N_GRAPHS, 64, 0, stream>>>(pool, start, scale, shift, Wout, bout, out);
}